// Round 3
// baseline (679.147 us; speedup 1.0000x reference)
//
#include <hip/hip_runtime.h>
#include <hip/hip_bf16.h>
#include <math.h>

#define NN   16384
#define EE   65536
#define DD   512
#define HH   4
#define FINN 7

typedef __attribute__((ext_vector_type(4))) float  floatx4;
typedef __attribute__((ext_vector_type(8))) float  floatx8;
typedef __attribute__((ext_vector_type(8))) short  shortx8;
typedef __attribute__((ext_vector_type(8))) unsigned short ushortx8;

// ---------------- helpers ----------------
__device__ inline float bf2f(unsigned short u) {
  return __uint_as_float(((unsigned)u) << 16);
}
__device__ inline unsigned short f2bf(float f) {
  unsigned u = __float_as_uint(f);
  unsigned r = (u + 0x7fffu + ((u >> 16) & 1u)) >> 16;
  return (unsigned short)r;
}
__device__ inline float wave_reduce_sum(float v) {
  #pragma unroll
  for (int off = 32; off > 0; off >>= 1) v += __shfl_down(v, off, 64);
  return v;
}
__device__ inline float wave_allreduce_sum(float v) {
  #pragma unroll
  for (int off = 32; off > 0; off >>= 1) v += __shfl_xor(v, off, 64);
  return v;
}
__device__ inline void async16(const unsigned short* g, unsigned short* l) {
  __builtin_amdgcn_global_load_lds(
      (const __attribute__((address_space(1))) void*)g,
      (__attribute__((address_space(3))) void*)l, 16, 0, 0);
}

// ---------------- CSR build ----------------
__global__ void k_count(const int* __restrict__ dst, int* __restrict__ cnt) {
  int e = blockIdx.x * 256 + threadIdx.x;
  if (e < EE) atomicAdd(&cnt[dst[e]], 1);
}

__global__ void k_scan(const int* __restrict__ cnt, int* __restrict__ offs) {
  __shared__ int sums[256];
  int t = threadIdx.x;
  const int chunk = NN / 256;
  int base = t * chunk;
  int s = 0;
  for (int i = 0; i < chunk; ++i) s += cnt[base + i];
  sums[t] = s;
  __syncthreads();
  for (int off = 1; off < 256; off <<= 1) {
    int v = (t >= off) ? sums[t - off] : 0;
    __syncthreads();
    sums[t] += v;
    __syncthreads();
  }
  int run = (t == 0) ? 0 : sums[t - 1];
  for (int i = 0; i < chunk; ++i) {
    offs[base + i] = run;
    run += cnt[base + i];
  }
  if (t == 255) offs[NN] = run;
}

__global__ void k_fill(const int* __restrict__ dst, const int* __restrict__ offs,
                       int* __restrict__ cursor, int* __restrict__ eids) {
  int e = blockIdx.x * 256 + threadIdx.x;
  if (e >= EE) return;
  int d = dst[e];
  int p = offs[d] + atomicAdd(&cursor[d], 1);
  eids[p] = e;
}

// ---------------- edge_attr mean ----------------
__global__ void k_edge_mean(const float* __restrict__ eattr, float* __restrict__ macc) {
  int tid = blockIdx.x * blockDim.x + threadIdx.x;
  int stride = gridDim.x * blockDim.x;
  float ax = 0.f, ay = 0.f, az = 0.f, aw = 0.f;
  for (int e = tid; e < EE; e += stride) {
    float4 v = ((const float4*)eattr)[e];
    ax += v.x; ay += v.y; az += v.z; aw += v.w;
  }
  ax = wave_reduce_sum(ax); ay = wave_reduce_sum(ay);
  az = wave_reduce_sum(az); aw = wave_reduce_sum(aw);
  if ((threadIdx.x & 63) == 0) {
    atomicAdd(&macc[0], ax); atomicAdd(&macc[1], ay);
    atomicAdd(&macc[2], az); atomicAdd(&macc[3], aw);
  }
}

// ------------- weight transpose+cast: W slice (K x N, ld) f32 -> Wt[N][K] bf16 -------
__global__ void k_transcast(const float* __restrict__ W, int ld,
                            unsigned short* __restrict__ Wt, int K, int N) {
  __shared__ float tile[32][33];
  int bx = blockIdx.x;
  int by = blockIdx.y;
  int tx = threadIdx.x & 31, ty = threadIdx.x >> 5;
  #pragma unroll
  for (int i = 0; i < 32; i += 8)
    tile[ty + i][tx] = W[(size_t)(by * 32 + ty + i) * ld + bx * 32 + tx];
  __syncthreads();
  #pragma unroll
  for (int i = 0; i < 32; i += 8)
    Wt[(size_t)(bx * 32 + ty + i) * K + by * 32 + tx] = f2bf(tile[tx][ty + i]);
}

// ------------- combined GAT bias ----------------
__global__ void k_bcomb(const float* __restrict__ bl, const float* __restrict__ br,
                        float* __restrict__ bc0, float* __restrict__ bc1) {
  int i = blockIdx.x * 256 + threadIdx.x;
  if (i >= 4096) return;
  int b = i >> 11, c = i & 2047;
  float v = (c < 1024) ? bl[b * 1024 + c] : br[b * 1024 + c - 1024];
  (b ? bc1 : bc0)[c] = v;
}

// ---------------- input projection ----------------
__global__ void k_proj(const float* __restrict__ x, const float* __restrict__ W,
                       const float* __restrict__ b, unsigned short* __restrict__ hbf) {
  int gid = blockIdx.x * 256 + threadIdx.x;
  if (gid >= NN * DD) return;
  int n = gid >> 9, d = gid & 511;
  const float* xr = x + n * FINN;
  float acc = b[d];
  #pragma unroll
  for (int k = 0; k < FINN; ++k) acc = fmaf(xr[k], W[k * DD + d], acc);
  hbf[gid] = f2bf(fmaxf(acc, 0.f));
}

// ---------------- bf16 MFMA GEMM with XOR-swizzled LDS ----------------
__global__ __launch_bounds__(256) void k_bgemm(
    const unsigned short* __restrict__ A, const unsigned short* __restrict__ Bt,
    const float* __restrict__ bias, void* __restrict__ Cout,
    int M, int Nc, int K, int act, int outbf) {
  __shared__ unsigned short As[128 * 64];
  __shared__ unsigned short Bs[128 * 64];
  const int tid = threadIdx.x;
  const int wv = tid >> 6;
  const int lane = tid & 63;
  const int row0 = blockIdx.y * 128;
  const int col0 = blockIdx.x * 128;
  const int wrow = (wv & 1) * 64;
  const int wcol = (wv >> 1) * 64;

  floatx4 acc[4][4];
  #pragma unroll
  for (int r = 0; r < 4; ++r)
    #pragma unroll
    for (int c = 0; c < 4; ++c)
      #pragma unroll
      for (int q = 0; q < 4; ++q) acc[r][c][q] = 0.f;

  const unsigned short* Ab = A + (size_t)row0 * K;
  const unsigned short* Bb = Bt + (size_t)col0 * K;
  const int lrow = lane >> 3;                       // 0..7 within segment
  const int lchunk = (lane & 7) ^ lrow;             // swizzled source k-chunk
  const int lk = lchunk * 8;                        // shorts

  const int frow = lane & 15;
  const int fx = lane >> 4;
  const int fsw = lane & 7;

  for (int k0 = 0; k0 < K; k0 += 64) {
    #pragma unroll
    for (int i = 0; i < 4; ++i) {
      int seg = i * 4 + wv;
      int r = seg * 8 + lrow;
      async16(Ab + (size_t)r * K + k0 + lk, &As[seg * 512]);
      async16(Bb + (size_t)r * K + k0 + lk, &Bs[seg * 512]);
    }
    __syncthreads();
    #pragma unroll
    for (int s = 0; s < 2; ++s) {
      int ch = ((s * 4 + fx) ^ fsw) * 8;
      shortx8 af[4], bfr[4];
      #pragma unroll
      for (int r = 0; r < 4; ++r)
        af[r] = *(const shortx8*)&As[(wrow + r * 16 + frow) * 64 + ch];
      #pragma unroll
      for (int c = 0; c < 4; ++c)
        bfr[c] = *(const shortx8*)&Bs[(wcol + c * 16 + frow) * 64 + ch];
      #pragma unroll
      for (int r = 0; r < 4; ++r)
        #pragma unroll
        for (int c = 0; c < 4; ++c)
          acc[r][c] = __builtin_amdgcn_mfma_f32_16x16x32_bf16(af[r], bfr[c], acc[r][c], 0, 0, 0);
    }
    __syncthreads();
  }

  #pragma unroll
  for (int r = 0; r < 4; ++r) {
    int rowb = row0 + wrow + r * 16 + (lane >> 4) * 4;
    #pragma unroll
    for (int c = 0; c < 4; ++c) {
      int col = col0 + wcol + c * 16 + (lane & 15);
      float bv = bias ? bias[col] : 0.f;
      #pragma unroll
      for (int q = 0; q < 4; ++q) {
        float v = acc[r][c][q] + bv;
        if (act) v = fmaxf(v, 0.f);
        if (outbf)
          ((unsigned short*)Cout)[(size_t)(rowb + q) * Nc + col] = f2bf(v);
        else
          ((float*)Cout)[(size_t)(rowb + q) * Nc + col] = v;
      }
    }
  }
}

// ------------- GINE aggregate (unroll-4 batched gathers for MLP) ----------------
// r9: per-wave serial chain was {gather -> wait -> 8 fma}; one load in flight.
// Batch 4 edges per iteration: 4 row gathers + 4 eattr issued together.
__global__ void k_gine_agg(const unsigned short* __restrict__ hbf,
                           const int* __restrict__ src, const float* __restrict__ eattr,
                           const float* __restrict__ geW, const float* __restrict__ geb,
                           const int* __restrict__ offs, const int* __restrict__ eids,
                           unsigned short* __restrict__ gbf) {
  int wave = (blockIdx.x * blockDim.x + threadIdx.x) >> 6;
  int lane = threadIdx.x & 63;
  if (wave >= NN) return;
  int n = wave;
  int cbase = lane * 8;
  floatx8 w0, w1, w2, w3, bb;
  #pragma unroll
  for (int j = 0; j < 8; ++j) {
    bb[j] = geb[cbase + j];
    w0[j] = geW[0 * DD + cbase + j];
    w1[j] = geW[1 * DD + cbase + j];
    w2[j] = geW[2 * DD + cbase + j];
    w3[j] = geW[3 * DD + cbase + j];
  }
  floatx8 acc = {0.f, 0.f, 0.f, 0.f, 0.f, 0.f, 0.f, 0.f};
  int beg = offs[n], end = offs[n + 1];
  int p = beg;
  for (; p + 4 <= end; p += 4) {
    int e0 = eids[p], e1 = eids[p + 1], e2 = eids[p + 2], e3 = eids[p + 3];
    int s0 = src[e0], s1 = src[e1], s2 = src[e2], s3 = src[e3];
    float4 ea0 = ((const float4*)eattr)[e0];
    float4 ea1 = ((const float4*)eattr)[e1];
    float4 ea2 = ((const float4*)eattr)[e2];
    float4 ea3 = ((const float4*)eattr)[e3];
    ushortx8 h0 = *(const ushortx8*)(hbf + (size_t)s0 * DD + cbase);
    ushortx8 h1 = *(const ushortx8*)(hbf + (size_t)s1 * DD + cbase);
    ushortx8 h2 = *(const ushortx8*)(hbf + (size_t)s2 * DD + cbase);
    ushortx8 h3 = *(const ushortx8*)(hbf + (size_t)s3 * DD + cbase);
    #pragma unroll
    for (int j = 0; j < 8; ++j) {
      float b0 = bb[j], j0 = w0[j], j1 = w1[j], j2 = w2[j], j3 = w3[j];
      float e0v = b0, e1v = b0, e2v = b0, e3v = b0;
      e0v = fmaf(ea0.x, j0, e0v); e0v = fmaf(ea0.y, j1, e0v);
      e0v = fmaf(ea0.z, j2, e0v); e0v = fmaf(ea0.w, j3, e0v);
      e1v = fmaf(ea1.x, j0, e1v); e1v = fmaf(ea1.y, j1, e1v);
      e1v = fmaf(ea1.z, j2, e1v); e1v = fmaf(ea1.w, j3, e1v);
      e2v = fmaf(ea2.x, j0, e2v); e2v = fmaf(ea2.y, j1, e2v);
      e2v = fmaf(ea2.z, j2, e2v); e2v = fmaf(ea2.w, j3, e2v);
      e3v = fmaf(ea3.x, j0, e3v); e3v = fmaf(ea3.y, j1, e3v);
      e3v = fmaf(ea3.z, j2, e3v); e3v = fmaf(ea3.w, j3, e3v);
      float a = acc[j];
      a += fmaxf(bf2f(h0[j]) + e0v, 0.f);
      a += fmaxf(bf2f(h1[j]) + e1v, 0.f);
      a += fmaxf(bf2f(h2[j]) + e2v, 0.f);
      a += fmaxf(bf2f(h3[j]) + e3v, 0.f);
      acc[j] = a;
    }
  }
  for (; p + 2 <= end; p += 2) {
    int e0 = eids[p], e1 = eids[p + 1];
    int s0 = src[e0], s1 = src[e1];
    float4 ea0 = ((const float4*)eattr)[e0];
    float4 ea1 = ((const float4*)eattr)[e1];
    ushortx8 h0 = *(const ushortx8*)(hbf + (size_t)s0 * DD + cbase);
    ushortx8 h1 = *(const ushortx8*)(hbf + (size_t)s1 * DD + cbase);
    #pragma unroll
    for (int j = 0; j < 8; ++j) {
      float b0 = bb[j], j0 = w0[j], j1 = w1[j], j2 = w2[j], j3 = w3[j];
      float e0v = b0, e1v = b0;
      e0v = fmaf(ea0.x, j0, e0v); e0v = fmaf(ea0.y, j1, e0v);
      e0v = fmaf(ea0.z, j2, e0v); e0v = fmaf(ea0.w, j3, e0v);
      e1v = fmaf(ea1.x, j0, e1v); e1v = fmaf(ea1.y, j1, e1v);
      e1v = fmaf(ea1.z, j2, e1v); e1v = fmaf(ea1.w, j3, e1v);
      float a = acc[j];
      a += fmaxf(bf2f(h0[j]) + e0v, 0.f);
      a += fmaxf(bf2f(h1[j]) + e1v, 0.f);
      acc[j] = a;
    }
  }
  for (; p < end; ++p) {
    int e = eids[p];
    int s = src[e];
    float4 ea = ((const float4*)eattr)[e];
    ushortx8 hv = *(const ushortx8*)(hbf + (size_t)s * DD + cbase);
    #pragma unroll
    for (int j = 0; j < 8; ++j) {
      float ev = bb[j];
      ev = fmaf(ea.x, w0[j], ev);
      ev = fmaf(ea.y, w1[j], ev);
      ev = fmaf(ea.z, w2[j], ev);
      ev = fmaf(ea.w, w3[j], ev);
      acc[j] += fmaxf(bf2f(hv[j]) + ev, 0.f);
    }
  }
  ushortx8 hn = *(const ushortx8*)(hbf + (size_t)n * DD + cbase);
  ushortx8 o;
  #pragma unroll
  for (int j = 0; j < 8; ++j) o[j] = f2bf(bf2f(hn[j]) + acc[j]);
  *(ushortx8*)(gbf + (size_t)n * DD + cbase) = o;
}

// -------- layer-0 LayerNorm ----------------
__global__ void k_ln0(const float* __restrict__ g, const unsigned short* __restrict__ res,
                      const float* __restrict__ gamma, const float* __restrict__ beta,
                      unsigned short* __restrict__ obf) {
  int wave = (blockIdx.x * blockDim.x + threadIdx.x) >> 6;
  int lane = threadIdx.x & 63;
  if (wave >= NN) return;
  int n = wave;
  int cbase = lane * 8;
  const float4* g4 = (const float4*)(g + (size_t)n * DD + cbase);
  ushortx8 rv = *(const ushortx8*)(res + (size_t)n * DD + cbase);
  float4 ga = g4[0], gb = g4[1];
  floatx8 v;
  v[0] = ga.x; v[1] = ga.y; v[2] = ga.z; v[3] = ga.w;
  v[4] = gb.x; v[5] = gb.y; v[6] = gb.z; v[7] = gb.w;
  float s = 0.f, sq = 0.f;
  #pragma unroll
  for (int j = 0; j < 8; ++j) {
    float t = fmaxf(v[j], 0.f) + bf2f(rv[j]);
    v[j] = t;
    s += t; sq += t * t;
  }
  s = wave_allreduce_sum(s);
  sq = wave_allreduce_sum(sq);
  float mu = s * (1.f / DD);
  float var = sq * (1.f / DD) - mu * mu;
  float rstd = rsqrtf(var + 1e-5f);
  ushortx8 ob;
  #pragma unroll
  for (int j = 0; j < 8; ++j)
    ob[j] = f2bf(fmaf((v[j] - mu) * rstd, gamma[cbase + j], beta[cbase + j]));
  *(ushortx8*)(obf + (size_t)n * DD + cbase) = ob;
}

// ======== fused GATv2 (r9): per-(node,head) waves + unroll-4 edge batching ========
// r8 proved occupancy is not the limiter (22->34% resident, dur flat at ~76us;
// VALU 40%, HBM 24%). The limiter is per-wave serial latency: one gather in
// flight per wave, then a 6-stage shuffle chain. r9 batches 4 edges per
// iteration: 4 row-gathers + 4 eattr loads issued together (4x outstanding
// loads per wave), 4 interleaved FMA chains, 4 interleaved shuffle chains
// (amortizes the ~300cy reduce latency 4-wide). Tail: 2-group then scalar.
// Block = 256 threads = 4 waves = 2 nodes x 2 heads. Grid = NN/2.
__global__ __launch_bounds__(256) void k_gat_fused(
    const unsigned short* __restrict__ xlr,
    const int* __restrict__ src,
    const int* __restrict__ offs, const int* __restrict__ eids,
    const float* __restrict__ eattr, const float* __restrict__ macc,
    const float* __restrict__ geW /*4x2048*/,
    const float* __restrict__ att /*4x512 (HxC)*/,
    float* __restrict__ B, unsigned short* __restrict__ Xbf,
    const float* __restrict__ gbias,
    const float* __restrict__ gamma, const float* __restrict__ beta,
    int batch) {
  __shared__ float lsum[2][512];          // head-1 normalized sums, per node-slot
  int wv = threadIdx.x >> 6;              // 0..3
  int lane = threadIdx.x & 63;
  int slot = wv >> 1;                     // node slot in block (0,1)
  int h = wv & 1;                         // head within batch
  int n = blockIdx.x * 2 + slot;
  int c8 = lane * 8;
  int hoff = h * 512;                     // xl/xr slice offset (shorts)
  int hc = (2 * batch + h) * 512 + c8;    // channel base in 2048-wide weights
  const float invE = 1.f / EE;
  float meax = macc[0] * invE, meay = macc[1] * invE;
  float meaz = macc[2] * invE, meaw = macc[3] * invE;
  int beg = offs[n], end = offs[n + 1];

  floatx8 w0, w1, w2, w3, at, xr;
  #pragma unroll
  for (int j = 0; j < 8; ++j) {
    w0[j] = geW[0 * (HH * DD) + hc + j];
    w1[j] = geW[1 * (HH * DD) + hc + j];
    w2[j] = geW[2 * (HH * DD) + hc + j];
    w3[j] = geW[3 * (HH * DD) + hc + j];
    at[j] = att[hc + j];
  }
  {
    ushortx8 rr = *(const ushortx8*)(xlr + (size_t)n * 2048 + 1024 + hoff + c8);
    #pragma unroll
    for (int j = 0; j < 8; ++j) xr[j] = bf2f(rr[j]);
  }

  float l;
  floatx8 acc;
  // ---- self-loop (edge attr = mean) ----
  {
    ushortx8 a = *(const ushortx8*)(xlr + (size_t)n * 2048 + hoff + c8);
    float z = 0.f;
    #pragma unroll
    for (int j = 0; j < 8; ++j) {
      float t = bf2f(a[j]) + xr[j];
      t = fmaf(meax, w0[j], t);
      t = fmaf(meay, w1[j], t);
      t = fmaf(meaz, w2[j], t);
      t = fmaf(meaw, w3[j], t);
      t = (t >= 0.f) ? t : 0.2f * t;
      z = fmaf(t, at[j], z);
    }
    #pragma unroll
    for (int off = 32; off > 0; off >>= 1) z += __shfl_xor(z, off, 64);
    float w = __expf(z);
    l = w;
    #pragma unroll
    for (int j = 0; j < 8; ++j) acc[j] = w * bf2f(a[j]);
  }
  // ---- CSR edges: 4-group, 2-group, scalar tail ----
  int p = beg;
  for (; p + 4 <= end; p += 4) {
    int e0 = eids[p], e1 = eids[p + 1], e2 = eids[p + 2], e3 = eids[p + 3];
    int s0 = src[e0], s1 = src[e1], s2 = src[e2], s3 = src[e3];
    float4 ea0 = ((const float4*)eattr)[e0];
    float4 ea1 = ((const float4*)eattr)[e1];
    float4 ea2 = ((const float4*)eattr)[e2];
    float4 ea3 = ((const float4*)eattr)[e3];
    ushortx8 a0 = *(const ushortx8*)(xlr + (size_t)s0 * 2048 + hoff + c8);
    ushortx8 a1 = *(const ushortx8*)(xlr + (size_t)s1 * 2048 + hoff + c8);
    ushortx8 a2 = *(const ushortx8*)(xlr + (size_t)s2 * 2048 + hoff + c8);
    ushortx8 a3 = *(const ushortx8*)(xlr + (size_t)s3 * 2048 + hoff + c8);
    float z0 = 0.f, z1 = 0.f, z2 = 0.f, z3 = 0.f;
    #pragma unroll
    for (int j = 0; j < 8; ++j) {
      float j0 = w0[j], j1 = w1[j], j2 = w2[j], j3 = w3[j];
      float aj = at[j], xj = xr[j];
      float t0 = bf2f(a0[j]) + xj;
      t0 = fmaf(ea0.x, j0, t0); t0 = fmaf(ea0.y, j1, t0);
      t0 = fmaf(ea0.z, j2, t0); t0 = fmaf(ea0.w, j3, t0);
      t0 = (t0 >= 0.f) ? t0 : 0.2f * t0;
      z0 = fmaf(t0, aj, z0);
      float t1 = bf2f(a1[j]) + xj;
      t1 = fmaf(ea1.x, j0, t1); t1 = fmaf(ea1.y, j1, t1);
      t1 = fmaf(ea1.z, j2, t1); t1 = fmaf(ea1.w, j3, t1);
      t1 = (t1 >= 0.f) ? t1 : 0.2f * t1;
      z1 = fmaf(t1, aj, z1);
      float t2 = bf2f(a2[j]) + xj;
      t2 = fmaf(ea2.x, j0, t2); t2 = fmaf(ea2.y, j1, t2);
      t2 = fmaf(ea2.z, j2, t2); t2 = fmaf(ea2.w, j3, t2);
      t2 = (t2 >= 0.f) ? t2 : 0.2f * t2;
      z2 = fmaf(t2, aj, z2);
      float t3 = bf2f(a3[j]) + xj;
      t3 = fmaf(ea3.x, j0, t3); t3 = fmaf(ea3.y, j1, t3);
      t3 = fmaf(ea3.z, j2, t3); t3 = fmaf(ea3.w, j3, t3);
      t3 = (t3 >= 0.f) ? t3 : 0.2f * t3;
      z3 = fmaf(t3, aj, z3);
    }
    #pragma unroll
    for (int off = 32; off > 0; off >>= 1) {
      z0 += __shfl_xor(z0, off, 64);
      z1 += __shfl_xor(z1, off, 64);
      z2 += __shfl_xor(z2, off, 64);
      z3 += __shfl_xor(z3, off, 64);
    }
    float g0 = __expf(z0), g1 = __expf(z1), g2 = __expf(z2), g3 = __expf(z3);
    l += (g0 + g1) + (g2 + g3);
    #pragma unroll
    for (int j = 0; j < 8; ++j) {
      float a = acc[j];
      a = fmaf(g0, bf2f(a0[j]), a);
      a = fmaf(g1, bf2f(a1[j]), a);
      a = fmaf(g2, bf2f(a2[j]), a);
      a = fmaf(g3, bf2f(a3[j]), a);
      acc[j] = a;
    }
  }
  for (; p + 2 <= end; p += 2) {
    int e0 = eids[p], e1 = eids[p + 1];
    int s0 = src[e0], s1 = src[e1];
    float4 ea0 = ((const float4*)eattr)[e0];
    float4 ea1 = ((const float4*)eattr)[e1];
    ushortx8 a0 = *(const ushortx8*)(xlr + (size_t)s0 * 2048 + hoff + c8);
    ushortx8 a1 = *(const ushortx8*)(xlr + (size_t)s1 * 2048 + hoff + c8);
    float z0 = 0.f, z1 = 0.f;
    #pragma unroll
    for (int j = 0; j < 8; ++j) {
      float j0 = w0[j], j1 = w1[j], j2 = w2[j], j3 = w3[j];
      float aj = at[j], xj = xr[j];
      float t0 = bf2f(a0[j]) + xj;
      t0 = fmaf(ea0.x, j0, t0); t0 = fmaf(ea0.y, j1, t0);
      t0 = fmaf(ea0.z, j2, t0); t0 = fmaf(ea0.w, j3, t0);
      t0 = (t0 >= 0.f) ? t0 : 0.2f * t0;
      z0 = fmaf(t0, aj, z0);
      float t1 = bf2f(a1[j]) + xj;
      t1 = fmaf(ea1.x, j0, t1); t1 = fmaf(ea1.y, j1, t1);
      t1 = fmaf(ea1.z, j2, t1); t1 = fmaf(ea1.w, j3, t1);
      t1 = (t1 >= 0.f) ? t1 : 0.2f * t1;
      z1 = fmaf(t1, aj, z1);
    }
    #pragma unroll
    for (int off = 32; off > 0; off >>= 1) {
      z0 += __shfl_xor(z0, off, 64);
      z1 += __shfl_xor(z1, off, 64);
    }
    float g0 = __expf(z0), g1 = __expf(z1);
    l += g0 + g1;
    #pragma unroll
    for (int j = 0; j < 8; ++j) {
      float a = acc[j];
      a = fmaf(g0, bf2f(a0[j]), a);
      a = fmaf(g1, bf2f(a1[j]), a);
      acc[j] = a;
    }
  }
  for (; p < end; ++p) {
    int e = eids[p];
    int s = src[e];
    float4 ea = ((const float4*)eattr)[e];
    ushortx8 a = *(const ushortx8*)(xlr + (size_t)s * 2048 + hoff + c8);
    float z = 0.f;
    #pragma unroll
    for (int j = 0; j < 8; ++j) {
      float t = bf2f(a[j]) + xr[j];
      t = fmaf(ea.x, w0[j], t);
      t = fmaf(ea.y, w1[j], t);
      t = fmaf(ea.z, w2[j], t);
      t = fmaf(ea.w, w3[j], t);
      t = (t >= 0.f) ? t : 0.2f * t;
      z = fmaf(t, at[j], z);
    }
    #pragma unroll
    for (int off = 32; off > 0; off >>= 1) z += __shfl_xor(z, off, 64);
    float w = __expf(z);
    l += w;
    #pragma unroll
    for (int j = 0; j < 8; ++j) acc[j] = fmaf(w, bf2f(a[j]), acc[j]);
  }

  float inv = 1.f / (l + 1e-16f);
  // head-1 waves publish their normalized sums; head-0 waves combine.
  if (h) {
    #pragma unroll
    for (int j = 0; j < 8; ++j) lsum[slot][c8 + j] = acc[j] * inv;
  }
  __syncthreads();
  if (h) return;

  floatx8 hsum;
  #pragma unroll
  for (int j = 0; j < 8; ++j) hsum[j] = acc[j] * inv + lsum[slot][c8 + j];

  float* bp = B + (size_t)n * DD + c8;
  if (batch == 0) {
    float4 o0, o1;
    o0.x = hsum[0]; o0.y = hsum[1]; o0.z = hsum[2]; o0.w = hsum[3];
    o1.x = hsum[4]; o1.y = hsum[5]; o1.z = hsum[6]; o1.w = hsum[7];
    ((float4*)bp)[0] = o0;
    ((float4*)bp)[1] = o1;
    return;
  }
  // batch 1: mean over 4 heads, +bias, relu, +residual, LN, write bf16
  float4 b0 = ((const float4*)bp)[0];
  float4 b1 = ((const float4*)bp)[1];
  floatx8 prev;
  prev[0] = b0.x; prev[1] = b0.y; prev[2] = b0.z; prev[3] = b0.w;
  prev[4] = b1.x; prev[5] = b1.y; prev[6] = b1.z; prev[7] = b1.w;
  ushortx8 rv = *(const ushortx8*)(Xbf + (size_t)n * DD + c8);
  floatx8 v;
  float s = 0.f, sq = 0.f;
  #pragma unroll
  for (int j = 0; j < 8; ++j) {
    float g = (prev[j] + hsum[j]) * 0.25f + gbias[c8 + j];
    float val = fmaxf(g, 0.f) + bf2f(rv[j]);
    v[j] = val;
    s += val; sq += val * val;
  }
  s = wave_allreduce_sum(s);
  sq = wave_allreduce_sum(sq);
  float mu = s * (1.f / DD);
  float var = sq * (1.f / DD) - mu * mu;
  float rstd = rsqrtf(var + 1e-5f);
  ushortx8 ob;
  #pragma unroll
  for (int j = 0; j < 8; ++j)
    ob[j] = f2bf(fmaf((v[j] - mu) * rstd, gamma[c8 + j], beta[c8 + j]));
  *(ushortx8*)(Xbf + (size_t)n * DD + c8) = ob;
}

// ---------------- GCN aggregate + fused bias/relu/res/LN ----------------
__global__ void k_dinv(const int* __restrict__ cnt, float* __restrict__ dinv) {
  int n = blockIdx.x * 256 + threadIdx.x;
  if (n < NN) dinv[n] = rsqrtf((float)cnt[n] + 1.0f);
}

__global__ void k_gcn_ln(const unsigned short* __restrict__ hw, const int* __restrict__ src,
                         const int* __restrict__ offs, const int* __restrict__ eids,
                         const float* __restrict__ dinv, const float* __restrict__ bias,
                         const float* __restrict__ gamma, const float* __restrict__ beta,
                         unsigned short* __restrict__ Xbf, float* __restrict__ outf) {
  int wave = (blockIdx.x * blockDim.x + threadIdx.x) >> 6;
  int lane = threadIdx.x & 63;
  if (wave >= NN) return;
  int n = wave;
  int cbase = lane * 8;
  float dn = dinv[n];
  floatx8 acc;
  {
    float wself = dn * dn;
    ushortx8 hv = *(const ushortx8*)(hw + (size_t)n * DD + cbase);
    #pragma unroll
    for (int j = 0; j < 8; ++j) acc[j] = wself * bf2f(hv[j]);
  }
  int beg = offs[n], end = offs[n + 1];
  int p = beg;
  for (; p + 4 <= end; p += 4) {
    int e0 = eids[p], e1 = eids[p + 1], e2 = eids[p + 2], e3 = eids[p + 3];
    int s0 = src[e0], s1 = src[e1], s2 = src[e2], s3 = src[e3];
    float d0 = dinv[s0], d1 = dinv[s1], d2 = dinv[s2], d3 = dinv[s3];
    ushortx8 h0 = *(const ushortx8*)(hw + (size_t)s0 * DD + cbase);
    ushortx8 h1 = *(const ushortx8*)(hw + (size_t)s1 * DD + cbase);
    ushortx8 h2 = *(const ushortx8*)(hw + (size_t)s2 * DD + cbase);
    ushortx8 h3 = *(const ushortx8*)(hw + (size_t)s3 * DD + cbase);
    float g0 = d0 * dn, g1 = d1 * dn, g2 = d2 * dn, g3 = d3 * dn;
    #pragma unroll
    for (int j = 0; j < 8; ++j) {
      float a = acc[j];
      a = fmaf(g0, bf2f(h0[j]), a);
      a = fmaf(g1, bf2f(h1[j]), a);
      a = fmaf(g2, bf2f(h2[j]), a);
      a = fmaf(g3, bf2f(h3[j]), a);
      acc[j] = a;
    }
  }
  for (; p + 2 <= end; p += 2) {
    int e0 = eids[p], e1 = eids[p + 1];
    int s0 = src[e0], s1 = src[e1];
    float d0 = dinv[s0], d1 = dinv[s1];
    ushortx8 h0 = *(const ushortx8*)(hw + (size_t)s0 * DD + cbase);
    ushortx8 h1 = *(const ushortx8*)(hw + (size_t)s1 * DD + cbase);
    float g0 = d0 * dn, g1 = d1 * dn;
    #pragma unroll
    for (int j = 0; j < 8; ++j) {
      float a = acc[j];
      a = fmaf(g0, bf2f(h0[j]), a);
      a = fmaf(g1, bf2f(h1[j]), a);
      acc[j] = a;
    }
  }
  for (; p < end; ++p) {
    int e = eids[p];
    int s = src[e];
    float wgt = dinv[s] * dn;
    ushortx8 hv = *(const ushortx8*)(hw + (size_t)s * DD + cbase);
    #pragma unroll
    for (int j = 0; j < 8; ++j) acc[j] = fmaf(wgt, bf2f(hv[j]), acc[j]);
  }
  ushortx8 rv = *(const ushortx8*)(Xbf + (size_t)n * DD + cbase);
  floatx8 v;
  float s = 0.f, sq = 0.f;
  #pragma unroll
  for (int j = 0; j < 8; ++j) {
    float g = acc[j] + bias[cbase + j];
    float t = fmaxf(g, 0.f) + bf2f(rv[j]);
    v[j] = t;
    s += t; sq += t * t;
  }
  s = wave_allreduce_sum(s);
  sq = wave_allreduce_sum(sq);
  float mu = s * (1.f / DD);
  float var = sq * (1.f / DD) - mu * mu;
  float rstd = rsqrtf(var + 1e-5f);
  if (outf) {
    float4* o4 = (float4*)(outf + (size_t)n * DD + cbase);
    float4 oa, ob4;
    oa.x = fmaf((v[0] - mu) * rstd, gamma[cbase + 0], beta[cbase + 0]);
    oa.y = fmaf((v[1] - mu) * rstd, gamma[cbase + 1], beta[cbase + 1]);
    oa.z = fmaf((v[2] - mu) * rstd, gamma[cbase + 2], beta[cbase + 2]);
    oa.w = fmaf((v[3] - mu) * rstd, gamma[cbase + 3], beta[cbase + 3]);
    ob4.x = fmaf((v[4] - mu) * rstd, gamma[cbase + 4], beta[cbase + 4]);
    ob4.y = fmaf((v[5] - mu) * rstd, gamma[cbase + 5], beta[cbase + 5]);
    ob4.z = fmaf((v[6] - mu) * rstd, gamma[cbase + 6], beta[cbase + 6]);
    ob4.w = fmaf((v[7] - mu) * rstd, gamma[cbase + 7], beta[cbase + 7]);
    o4[0] = oa;
    o4[1] = ob4;
  } else {
    ushortx8 ob;
    #pragma unroll
    for (int j = 0; j < 8; ++j)
      ob[j] = f2bf(fmaf((v[j] - mu) * rstd, gamma[cbase + j], beta[cbase + j]));
    *(ushortx8*)(Xbf + (size_t)n * DD + cbase) = ob;
  }
}

// ---------------- host-side launcher ----------------
static void launch_bgemm(const unsigned short* A, const unsigned short* Bt,
                         const float* bias, void* C, int M, int Nc, int K,
                         int act, int outbf, hipStream_t stream) {
  dim3 grid(Nc / 128, M / 128);
  k_bgemm<<<grid, 256, 0, stream>>>(A, Bt, bias, C, M, Nc, K, act, outbf);
}

extern "C" void kernel_launch(void* const* d_in, const int* in_sizes, int n_in,
                              void* d_out, int out_size, void* d_ws, size_t ws_size,
                              hipStream_t stream) {
  const float* x       = (const float*)d_in[0];
  const int*   eidx    = (const int*)d_in[1];
  const float* eattr   = (const float*)d_in[2];
  const float* Wproj   = (const float*)d_in[3];
  const float* bproj   = (const float*)d_in[4];
  const float* geW     = (const float*)d_in[5];
  const float* geb     = (const float*)d_in[6];
  const float* gW1     = (const float*)d_in[7];
  const float* gb1     = (const float*)d_in[8];
  const float* gW2     = (const float*)d_in[9];
  const float* gb2     = (const float*)d_in[10];
  const float* gatWl   = (const float*)d_in[11];
  const float* gatbl   = (const float*)d_in[12];
  const float* gatWr   = (const float*)d_in[13];
  const float* gatbr   = (const float*)d_in[14];
  const float* gateW   = (const float*)d_in[15];
  const float* gatatt  = (const float*)d_in[16];
  const float* gatbias = (const float*)d_in[17];
  const float* gcn1W   = (const float*)d_in[18];
  const float* gcn1b   = (const float*)d_in[19];
  const float* gcn2W   = (const float*)d_in[20];
  const float* gcn2b   = (const float*)d_in[21];
  const float* lgamma  = (const float*)d_in[22];
  const float* lbeta   = (const float*)d_in[23];
  const int* srcArr = eidx;
  const int* dstArr = eidx + EE;

  // ---- workspace carving (~119 MB) ----
  char* p = (char*)d_ws;
  float* B            = (float*)p;          p += (size_t)NN * DD * 4;        // 32MB
  unsigned short* Xbf = (unsigned short*)p; p += (size_t)NN * DD * 2;        // 16MB
  unsigned short* U   = (unsigned short*)p; p += (size_t)NN * 2048 * 2;      // 64MB union
  unsigned short* w1t = (unsigned short*)p; p += (size_t)1024 * 512 * 2;
  unsigned short* w2t = (unsigned short*)p; p += (size_t)512 * 1024 * 2;
  unsigned short* wc0 = (unsigned short*)p; p += (size_t)2048 * 512 * 2;
  unsigned short* wc1 = (unsigned short*)p; p += (size_t)2048 * 512 * 2;
  unsigned short* g1t = (unsigned short*)p; p += (size_t)512 * 512 * 2;
  unsigned short* g2t = (unsigned short*)p; p += (size_t)512 * 512 * 2;
  float* bc0      = (float*)p;          p += 2048 * 4;
  float* bc1      = (float*)p;          p += 2048 * 4;
  float* macc     = (float*)p;          p += 4 * 4;
  float* dinv     = (float*)p;          p += (size_t)NN * 4;
  int*   cnt      = (int*)p;            p += (size_t)NN * 4;
  int*   offs     = (int*)p;            p += (size_t)(NN + 1) * 4 + 12;
  int*   cursor   = (int*)p;            p += (size_t)NN * 4;
  int*   eids     = (int*)p;            p += (size_t)EE * 4;

  unsigned short* Zbf = U;                    // NN x 512 (GINE agg out)
  unsigned short* Ybf = U + (size_t)NN * 512; // NN x 1024 (MLP mid)
  unsigned short* XLR = U;                    // NN x 2048 (GAT xl|xr, 2 heads)
  unsigned short* hw  = U;                    // NN x 512 (GCN h@W)

  hipMemsetAsync(cnt, 0, NN * sizeof(int), stream);
  hipMemsetAsync(cursor, 0, NN * sizeof(int), stream);
  hipMemsetAsync(macc, 0, 4 * sizeof(float), stream);

  k_count<<<EE / 256, 256, 0, stream>>>(dstArr, cnt);
  k_scan<<<1, 256, 0, stream>>>(cnt, offs);
  k_fill<<<EE / 256, 256, 0, stream>>>(dstArr, offs, cursor, eids);
  k_edge_mean<<<64, 256, 0, stream>>>(eattr, macc);

  // weight prep
  {
    k_transcast<<<dim3(1024 / 32, 512 / 32), 256, 0, stream>>>(gW1, 1024, w1t, 512, 1024);
    k_transcast<<<dim3(512 / 32, 1024 / 32), 256, 0, stream>>>(gW2, 512, w2t, 1024, 512);
    k_transcast<<<dim3(1024 / 32, 512 / 32), 256, 0, stream>>>(gatWl, 2048, wc0, 512, 1024);
    k_transcast<<<dim3(1024 / 32, 512 / 32), 256, 0, stream>>>(gatWr, 2048, wc0 + (size_t)1024 * 512, 512, 1024);
    k_transcast<<<dim3(1024 / 32, 512 / 32), 256, 0, stream>>>(gatWl + 1024, 2048, wc1, 512, 1024);
    k_transcast<<<dim3(1024 / 32, 512 / 32), 256, 0, stream>>>(gatWr + 1024, 2048, wc1 + (size_t)1024 * 512, 512, 1024);
    k_transcast<<<dim3(512 / 32, 512 / 32), 256, 0, stream>>>(gcn1W, 512, g1t, 512, 512);
    k_transcast<<<dim3(512 / 32, 512 / 32), 256, 0, stream>>>(gcn2W, 512, g2t, 512, 512);
    k_bcomb<<<16, 256, 0, stream>>>(gatbl, gatbr, bc0, bc1);
  }

  // input projection (bf16 only)
  k_proj<<<NN * DD / 256, 256, 0, stream>>>(x, Wproj, bproj, Xbf);

  // ---- layer 0: GINEConv + MLP + LN ----
  k_gine_agg<<<NN / 4, 256, 0, stream>>>(Xbf, srcArr, eattr, geW, geb, offs, eids, Zbf);
  launch_bgemm(Zbf, w1t, gb1, Ybf, NN, 1024, 512, 1, 1, stream);
  launch_bgemm(Ybf, w2t, gb2, B, NN, 512, 1024, 0, 0, stream);
  k_ln0<<<NN / 4, 256, 0, stream>>>(B, Xbf, lgamma, lbeta, Xbf);

  // ---- layer 1: GATv2, two 2-head batches; per-(node,head) waves ----
  for (int b = 0; b < 2; ++b) {
    launch_bgemm(Xbf, b ? wc1 : wc0, b ? bc1 : bc0, XLR, NN, 2048, 512, 0, 1, stream);
    k_gat_fused<<<NN / 2, 256, 0, stream>>>(XLR, srcArr, offs, eids, eattr, macc,
                                            gateW, gatatt, B, Xbf, gatbias,
                                            lgamma + DD, lbeta + DD, b);
  }

  // ---- layers 2,3: GCN (aggregate + fused LN) ----
  k_dinv<<<NN / 256, 256, 0, stream>>>(cnt, dinv);
  launch_bgemm(Xbf, g1t, nullptr, hw, NN, 512, 512, 0, 1, stream);
  k_gcn_ln<<<NN / 4, 256, 0, stream>>>(hw, srcArr, offs, eids, dinv, gcn1b,
                                       lgamma + 2 * DD, lbeta + 2 * DD, Xbf, nullptr);
  launch_bgemm(Xbf, g2t, nullptr, hw, NN, 512, 512, 0, 1, stream);
  k_gcn_ln<<<NN / 4, 256, 0, stream>>>(hw, srcArr, offs, eids, dinv, gcn2b,
                                       lgamma + 3 * DD, lbeta + 3 * DD, Xbf, (float*)d_out);
}

// Round 4
// 588.380 us; speedup vs baseline: 1.1543x; 1.1543x over previous
//
#include <hip/hip_runtime.h>
#include <hip/hip_bf16.h>
#include <math.h>

#define NN   16384
#define EE   65536
#define DD   512
#define HH   4
#define FINN 7

typedef __attribute__((ext_vector_type(4))) float  floatx4;
typedef __attribute__((ext_vector_type(8))) float  floatx8;
typedef __attribute__((ext_vector_type(8))) short  shortx8;
typedef __attribute__((ext_vector_type(8))) unsigned short ushortx8;

// ---------------- helpers ----------------
__device__ inline float bf2f(unsigned short u) {
  return __uint_as_float(((unsigned)u) << 16);
}
__device__ inline unsigned short f2bf(float f) {
  unsigned u = __float_as_uint(f);
  unsigned r = (u + 0x7fffu + ((u >> 16) & 1u)) >> 16;
  return (unsigned short)r;
}
__device__ inline float wave_reduce_sum(float v) {
  #pragma unroll
  for (int off = 32; off > 0; off >>= 1) v += __shfl_down(v, off, 64);
  return v;
}
__device__ inline float wave_allreduce_sum(float v) {
  #pragma unroll
  for (int off = 32; off > 0; off >>= 1) v += __shfl_xor(v, off, 64);
  return v;
}
__device__ inline void async16(const unsigned short* g, unsigned short* l) {
  __builtin_amdgcn_global_load_lds(
      (const __attribute__((address_space(1))) void*)g,
      (__attribute__((address_space(3))) void*)l, 16, 0, 0);
}

// ---------------- CSR build ----------------
__global__ void k_count(const int* __restrict__ dst, int* __restrict__ cnt) {
  int e = blockIdx.x * 256 + threadIdx.x;
  if (e < EE) atomicAdd(&cnt[dst[e]], 1);
}

__global__ void k_scan(const int* __restrict__ cnt, int* __restrict__ offs) {
  __shared__ int sums[256];
  int t = threadIdx.x;
  const int chunk = NN / 256;
  int base = t * chunk;
  int s = 0;
  for (int i = 0; i < chunk; ++i) s += cnt[base + i];
  sums[t] = s;
  __syncthreads();
  for (int off = 1; off < 256; off <<= 1) {
    int v = (t >= off) ? sums[t - off] : 0;
    __syncthreads();
    sums[t] += v;
    __syncthreads();
  }
  int run = (t == 0) ? 0 : sums[t - 1];
  for (int i = 0; i < chunk; ++i) {
    offs[base + i] = run;
    run += cnt[base + i];
  }
  if (t == 255) offs[NN] = run;
}

// r10: k_fill now materializes CSR-ordered src ids and edge attrs, removing
// the eids->src->eattr dependent-load levels from every gather kernel.
__global__ void k_fill(const int* __restrict__ dst, const int* __restrict__ src,
                       const float* __restrict__ eattr, const int* __restrict__ offs,
                       int* __restrict__ cursor, int* __restrict__ srcs,
                       float4* __restrict__ ea4) {
  int e = blockIdx.x * 256 + threadIdx.x;
  if (e >= EE) return;
  int d = dst[e];
  int p = offs[d] + atomicAdd(&cursor[d], 1);
  srcs[p] = src[e];
  ea4[p] = ((const float4*)eattr)[e];
}

// ---------------- edge_attr mean ----------------
__global__ void k_edge_mean(const float* __restrict__ eattr, float* __restrict__ macc) {
  int tid = blockIdx.x * blockDim.x + threadIdx.x;
  int stride = gridDim.x * blockDim.x;
  float ax = 0.f, ay = 0.f, az = 0.f, aw = 0.f;
  for (int e = tid; e < EE; e += stride) {
    float4 v = ((const float4*)eattr)[e];
    ax += v.x; ay += v.y; az += v.z; aw += v.w;
  }
  ax = wave_reduce_sum(ax); ay = wave_reduce_sum(ay);
  az = wave_reduce_sum(az); aw = wave_reduce_sum(aw);
  if ((threadIdx.x & 63) == 0) {
    atomicAdd(&macc[0], ax); atomicAdd(&macc[1], ay);
    atomicAdd(&macc[2], az); atomicAdd(&macc[3], aw);
  }
}

// ------------- weight transpose+cast: W slice (K x N, ld) f32 -> Wt[N][K] bf16 -------
__global__ void k_transcast(const float* __restrict__ W, int ld,
                            unsigned short* __restrict__ Wt, int K, int N) {
  __shared__ float tile[32][33];
  int bx = blockIdx.x;
  int by = blockIdx.y;
  int tx = threadIdx.x & 31, ty = threadIdx.x >> 5;
  #pragma unroll
  for (int i = 0; i < 32; i += 8)
    tile[ty + i][tx] = W[(size_t)(by * 32 + ty + i) * ld + bx * 32 + tx];
  __syncthreads();
  #pragma unroll
  for (int i = 0; i < 32; i += 8)
    Wt[(size_t)(bx * 32 + ty + i) * K + by * 32 + tx] = f2bf(tile[tx][ty + i]);
}

// ------------- combined GAT bias ----------------
__global__ void k_bcomb(const float* __restrict__ bl, const float* __restrict__ br,
                        float* __restrict__ bc0, float* __restrict__ bc1) {
  int i = blockIdx.x * 256 + threadIdx.x;
  if (i >= 4096) return;
  int b = i >> 11, c = i & 2047;
  float v = (c < 1024) ? bl[b * 1024 + c] : br[b * 1024 + c - 1024];
  (b ? bc1 : bc0)[c] = v;
}

// ---------------- input projection ----------------
__global__ void k_proj(const float* __restrict__ x, const float* __restrict__ W,
                       const float* __restrict__ b, unsigned short* __restrict__ hbf) {
  int gid = blockIdx.x * 256 + threadIdx.x;
  if (gid >= NN * DD) return;
  int n = gid >> 9, d = gid & 511;
  const float* xr = x + n * FINN;
  float acc = b[d];
  #pragma unroll
  for (int k = 0; k < FINN; ++k) acc = fmaf(xr[k], W[k * DD + d], acc);
  hbf[gid] = f2bf(fmaxf(acc, 0.f));
}

// ---------------- bf16 MFMA GEMM with XOR-swizzled LDS + XCD block swizzle ----------
__global__ __launch_bounds__(256) void k_bgemm(
    const unsigned short* __restrict__ A, const unsigned short* __restrict__ Bt,
    const float* __restrict__ bias, void* __restrict__ Cout,
    int M, int Nc, int K, int act, int outbf) {
  __shared__ unsigned short As[128 * 64];
  __shared__ unsigned short Bs[128 * 64];
  const int tid = threadIdx.x;
  const int wv = tid >> 6;
  const int lane = tid & 63;
  // bijective XCD swizzle (nwg % 8 == 0 for all our launches): groups each
  // XCD's round-robin share onto a contiguous chunk of tile space -> A/B
  // panels stay in one XCD's L2 instead of being fetched by all 8.
  int gx = gridDim.x;
  int nwg = gx * gridDim.y;
  int wg = blockIdx.y * gx + blockIdx.x;
  if ((nwg & 7) == 0) {
    int cpx = nwg >> 3;
    wg = (wg & 7) * cpx + (wg >> 3);
  }
  const int row0 = (wg / gx) * 128;
  const int col0 = (wg % gx) * 128;
  const int wrow = (wv & 1) * 64;
  const int wcol = (wv >> 1) * 64;

  floatx4 acc[4][4];
  #pragma unroll
  for (int r = 0; r < 4; ++r)
    #pragma unroll
    for (int c = 0; c < 4; ++c)
      #pragma unroll
      for (int q = 0; q < 4; ++q) acc[r][c][q] = 0.f;

  const unsigned short* Ab = A + (size_t)row0 * K;
  const unsigned short* Bb = Bt + (size_t)col0 * K;
  const int lrow = lane >> 3;                       // 0..7 within segment
  const int lchunk = (lane & 7) ^ lrow;             // swizzled source k-chunk
  const int lk = lchunk * 8;                        // shorts

  const int frow = lane & 15;
  const int fx = lane >> 4;
  const int fsw = lane & 7;

  for (int k0 = 0; k0 < K; k0 += 64) {
    #pragma unroll
    for (int i = 0; i < 4; ++i) {
      int seg = i * 4 + wv;
      int r = seg * 8 + lrow;
      async16(Ab + (size_t)r * K + k0 + lk, &As[seg * 512]);
      async16(Bb + (size_t)r * K + k0 + lk, &Bs[seg * 512]);
    }
    __syncthreads();
    #pragma unroll
    for (int s = 0; s < 2; ++s) {
      int ch = ((s * 4 + fx) ^ fsw) * 8;
      shortx8 af[4], bfr[4];
      #pragma unroll
      for (int r = 0; r < 4; ++r)
        af[r] = *(const shortx8*)&As[(wrow + r * 16 + frow) * 64 + ch];
      #pragma unroll
      for (int c = 0; c < 4; ++c)
        bfr[c] = *(const shortx8*)&Bs[(wcol + c * 16 + frow) * 64 + ch];
      #pragma unroll
      for (int r = 0; r < 4; ++r)
        #pragma unroll
        for (int c = 0; c < 4; ++c)
          acc[r][c] = __builtin_amdgcn_mfma_f32_16x16x32_bf16(af[r], bfr[c], acc[r][c], 0, 0, 0);
    }
    __syncthreads();
  }

  #pragma unroll
  for (int r = 0; r < 4; ++r) {
    int rowb = row0 + wrow + r * 16 + (lane >> 4) * 4;
    #pragma unroll
    for (int c = 0; c < 4; ++c) {
      int col = col0 + wcol + c * 16 + (lane & 15);
      float bv = bias ? bias[col] : 0.f;
      #pragma unroll
      for (int q = 0; q < 4; ++q) {
        float v = acc[r][c][q] + bv;
        if (act) v = fmaxf(v, 0.f);
        if (outbf)
          ((unsigned short*)Cout)[(size_t)(rowb + q) * Nc + col] = f2bf(v);
        else
          ((float*)Cout)[(size_t)(rowb + q) * Nc + col] = v;
      }
    }
  }
}

// ------------- GINE aggregate (r10: CSR-ordered srcs/ea4, no indirection) --------
__global__ void k_gine_agg(const unsigned short* __restrict__ hbf,
                           const int* __restrict__ srcs, const float4* __restrict__ ea4,
                           const float* __restrict__ geW, const float* __restrict__ geb,
                           const int* __restrict__ offs,
                           unsigned short* __restrict__ gbf) {
  int wave = (blockIdx.x * blockDim.x + threadIdx.x) >> 6;
  int lane = threadIdx.x & 63;
  if (wave >= NN) return;
  int n = wave;
  int cbase = lane * 8;
  floatx8 w0, w1, w2, w3, bb;
  #pragma unroll
  for (int j = 0; j < 8; ++j) {
    bb[j] = geb[cbase + j];
    w0[j] = geW[0 * DD + cbase + j];
    w1[j] = geW[1 * DD + cbase + j];
    w2[j] = geW[2 * DD + cbase + j];
    w3[j] = geW[3 * DD + cbase + j];
  }
  floatx8 acc = {0.f, 0.f, 0.f, 0.f, 0.f, 0.f, 0.f, 0.f};
  int beg = offs[n], end = offs[n + 1];
  int scur = srcs[beg];                    // padded array: srcs[EE] readable
  for (int p = beg; p < end; ++p) {
    int s = scur;
    scur = srcs[p + 1];                    // branchless one-ahead (padded)
    float4 ea = ea4[p];
    ushortx8 hv = *(const ushortx8*)(hbf + (size_t)s * DD + cbase);
    #pragma unroll
    for (int j = 0; j < 8; ++j) {
      float ev = bb[j];
      ev = fmaf(ea.x, w0[j], ev);
      ev = fmaf(ea.y, w1[j], ev);
      ev = fmaf(ea.z, w2[j], ev);
      ev = fmaf(ea.w, w3[j], ev);
      acc[j] += fmaxf(bf2f(hv[j]) + ev, 0.f);
    }
  }
  ushortx8 hn = *(const ushortx8*)(hbf + (size_t)n * DD + cbase);
  ushortx8 o;
  #pragma unroll
  for (int j = 0; j < 8; ++j) o[j] = f2bf(bf2f(hn[j]) + acc[j]);
  *(ushortx8*)(gbf + (size_t)n * DD + cbase) = o;
}

// -------- layer-0 LayerNorm ----------------
__global__ void k_ln0(const float* __restrict__ g, const unsigned short* __restrict__ res,
                      const float* __restrict__ gamma, const float* __restrict__ beta,
                      unsigned short* __restrict__ obf) {
  int wave = (blockIdx.x * blockDim.x + threadIdx.x) >> 6;
  int lane = threadIdx.x & 63;
  if (wave >= NN) return;
  int n = wave;
  int cbase = lane * 8;
  const float4* g4 = (const float4*)(g + (size_t)n * DD + cbase);
  ushortx8 rv = *(const ushortx8*)(res + (size_t)n * DD + cbase);
  float4 ga = g4[0], gb = g4[1];
  floatx8 v;
  v[0] = ga.x; v[1] = ga.y; v[2] = ga.z; v[3] = ga.w;
  v[4] = gb.x; v[5] = gb.y; v[6] = gb.z; v[7] = gb.w;
  float s = 0.f, sq = 0.f;
  #pragma unroll
  for (int j = 0; j < 8; ++j) {
    float t = fmaxf(v[j], 0.f) + bf2f(rv[j]);
    v[j] = t;
    s += t; sq += t * t;
  }
  s = wave_allreduce_sum(s);
  sq = wave_allreduce_sum(sq);
  float mu = s * (1.f / DD);
  float var = sq * (1.f / DD) - mu * mu;
  float rstd = rsqrtf(var + 1e-5f);
  ushortx8 ob;
  #pragma unroll
  for (int j = 0; j < 8; ++j)
    ob[j] = f2bf(fmaf((v[j] - mu) * rstd, gamma[cbase + j], beta[cbase + j]));
  *(ushortx8*)(obf + (size_t)n * DD + cbase) = ob;
}

// ======== fused GATv2 (r10): per-(node,head) waves, CSR-ordered srcs/ea4 ========
// r2's 76us form (proven stable) minus two dependent-load levels per edge:
// srcs[p]/ea4[p] are sequential affine loads (L1-resident), leaving the 1KB
// node-row read as the only gather on the per-edge critical path.
// Block = 256 threads = 4 waves = 2 nodes x 2 heads. Grid = NN/2.
__global__ __launch_bounds__(256) void k_gat_fused(
    const unsigned short* __restrict__ xlr,
    const int* __restrict__ srcs,
    const int* __restrict__ offs, const float4* __restrict__ ea4,
    const float* __restrict__ macc,
    const float* __restrict__ geW /*4x2048*/,
    const float* __restrict__ att /*4x512 (HxC)*/,
    float* __restrict__ B, unsigned short* __restrict__ Xbf,
    const float* __restrict__ gbias,
    const float* __restrict__ gamma, const float* __restrict__ beta,
    int batch) {
  __shared__ float lsum[2][512];          // head-1 normalized sums, per node-slot
  int wv = threadIdx.x >> 6;              // 0..3
  int lane = threadIdx.x & 63;
  int slot = wv >> 1;                     // node slot in block (0,1)
  int h = wv & 1;                         // head within batch
  int n = blockIdx.x * 2 + slot;
  int c8 = lane * 8;
  int hoff = h * 512;                     // xl/xr slice offset (shorts)
  int hc = (2 * batch + h) * 512 + c8;    // channel base in 2048-wide weights
  const float invE = 1.f / EE;
  float meax = macc[0] * invE, meay = macc[1] * invE;
  float meaz = macc[2] * invE, meaw = macc[3] * invE;
  int beg = offs[n], end = offs[n + 1];

  floatx8 w0, w1, w2, w3, at, xr;
  #pragma unroll
  for (int j = 0; j < 8; ++j) {
    w0[j] = geW[0 * (HH * DD) + hc + j];
    w1[j] = geW[1 * (HH * DD) + hc + j];
    w2[j] = geW[2 * (HH * DD) + hc + j];
    w3[j] = geW[3 * (HH * DD) + hc + j];
    at[j] = att[hc + j];
  }
  {
    ushortx8 rr = *(const ushortx8*)(xlr + (size_t)n * 2048 + 1024 + hoff + c8);
    #pragma unroll
    for (int j = 0; j < 8; ++j) xr[j] = bf2f(rr[j]);
  }

  float l;
  floatx8 acc;
  // ---- self-loop (edge attr = mean) ----
  {
    ushortx8 a = *(const ushortx8*)(xlr + (size_t)n * 2048 + hoff + c8);
    float z = 0.f;
    #pragma unroll
    for (int j = 0; j < 8; ++j) {
      float t = bf2f(a[j]) + xr[j];
      t = fmaf(meax, w0[j], t);
      t = fmaf(meay, w1[j], t);
      t = fmaf(meaz, w2[j], t);
      t = fmaf(meaw, w3[j], t);
      t = (t >= 0.f) ? t : 0.2f * t;
      z = fmaf(t, at[j], z);
    }
    #pragma unroll
    for (int off = 32; off > 0; off >>= 1) z += __shfl_xor(z, off, 64);
    float w = __expf(z);
    l = w;
    #pragma unroll
    for (int j = 0; j < 8; ++j) acc[j] = w * bf2f(a[j]);
  }
  // ---- CSR edges (this head only; branchless one-ahead src) ----
  int scur = srcs[beg];                    // padded: srcs[EE] readable
  for (int p = beg; p < end; ++p) {
    int s = scur;
    scur = srcs[p + 1];
    float4 ea = ea4[p];
    ushortx8 a = *(const ushortx8*)(xlr + (size_t)s * 2048 + hoff + c8);
    float z = 0.f;
    #pragma unroll
    for (int j = 0; j < 8; ++j) {
      float t = bf2f(a[j]) + xr[j];
      t = fmaf(ea.x, w0[j], t);
      t = fmaf(ea.y, w1[j], t);
      t = fmaf(ea.z, w2[j], t);
      t = fmaf(ea.w, w3[j], t);
      t = (t >= 0.f) ? t : 0.2f * t;
      z = fmaf(t, at[j], z);
    }
    #pragma unroll
    for (int off = 32; off > 0; off >>= 1) z += __shfl_xor(z, off, 64);
    float w = __expf(z);
    l += w;
    #pragma unroll
    for (int j = 0; j < 8; ++j) acc[j] = fmaf(w, bf2f(a[j]), acc[j]);
  }

  float inv = 1.f / (l + 1e-16f);
  // head-1 waves publish their normalized sums; head-0 waves combine.
  if (h) {
    #pragma unroll
    for (int j = 0; j < 8; ++j) lsum[slot][c8 + j] = acc[j] * inv;
  }
  __syncthreads();
  if (h) return;

  floatx8 hsum;
  #pragma unroll
  for (int j = 0; j < 8; ++j) hsum[j] = acc[j] * inv + lsum[slot][c8 + j];

  float* bp = B + (size_t)n * DD + c8;
  if (batch == 0) {
    float4 o0, o1;
    o0.x = hsum[0]; o0.y = hsum[1]; o0.z = hsum[2]; o0.w = hsum[3];
    o1.x = hsum[4]; o1.y = hsum[5]; o1.z = hsum[6]; o1.w = hsum[7];
    ((float4*)bp)[0] = o0;
    ((float4*)bp)[1] = o1;
    return;
  }
  // batch 1: mean over 4 heads, +bias, relu, +residual, LN, write bf16
  float4 b0 = ((const float4*)bp)[0];
  float4 b1 = ((const float4*)bp)[1];
  floatx8 prev;
  prev[0] = b0.x; prev[1] = b0.y; prev[2] = b0.z; prev[3] = b0.w;
  prev[4] = b1.x; prev[5] = b1.y; prev[6] = b1.z; prev[7] = b1.w;
  ushortx8 rv = *(const ushortx8*)(Xbf + (size_t)n * DD + c8);
  floatx8 v;
  float s = 0.f, sq = 0.f;
  #pragma unroll
  for (int j = 0; j < 8; ++j) {
    float g = (prev[j] + hsum[j]) * 0.25f + gbias[c8 + j];
    float val = fmaxf(g, 0.f) + bf2f(rv[j]);
    v[j] = val;
    s += val; sq += val * val;
  }
  s = wave_allreduce_sum(s);
  sq = wave_allreduce_sum(sq);
  float mu = s * (1.f / DD);
  float var = sq * (1.f / DD) - mu * mu;
  float rstd = rsqrtf(var + 1e-5f);
  ushortx8 ob;
  #pragma unroll
  for (int j = 0; j < 8; ++j)
    ob[j] = f2bf(fmaf((v[j] - mu) * rstd, gamma[c8 + j], beta[c8 + j]));
  *(ushortx8*)(Xbf + (size_t)n * DD + c8) = ob;
}

// ---------------- GCN aggregate + fused bias/relu/res/LN ----------------
__global__ void k_dinv(const int* __restrict__ cnt, float* __restrict__ dinv) {
  int n = blockIdx.x * 256 + threadIdx.x;
  if (n < NN) dinv[n] = rsqrtf((float)cnt[n] + 1.0f);
}

// precompute dinv[src] in CSR order (removes the per-edge scalar gather)
__global__ void k_dsrc(const int* __restrict__ srcs, const float* __restrict__ dinv,
                       float* __restrict__ dinv_src) {
  int p = blockIdx.x * 256 + threadIdx.x;
  if (p < EE) dinv_src[p] = dinv[srcs[p]];
}

__global__ void k_gcn_ln(const unsigned short* __restrict__ hw, const int* __restrict__ srcs,
                         const int* __restrict__ offs, const float* __restrict__ dinv_src,
                         const float* __restrict__ dinv, const float* __restrict__ bias,
                         const float* __restrict__ gamma, const float* __restrict__ beta,
                         unsigned short* __restrict__ Xbf, float* __restrict__ outf) {
  int wave = (blockIdx.x * blockDim.x + threadIdx.x) >> 6;
  int lane = threadIdx.x & 63;
  if (wave >= NN) return;
  int n = wave;
  int cbase = lane * 8;
  float dn = dinv[n];
  floatx8 acc;
  {
    float wself = dn * dn;
    ushortx8 hv = *(const ushortx8*)(hw + (size_t)n * DD + cbase);
    #pragma unroll
    for (int j = 0; j < 8; ++j) acc[j] = wself * bf2f(hv[j]);
  }
  int beg = offs[n], end = offs[n + 1];
  int scur = srcs[beg];                    // padded
  for (int p = beg; p < end; ++p) {
    int s = scur;
    scur = srcs[p + 1];
    float wgt = dinv_src[p] * dn;
    ushortx8 hv = *(const ushortx8*)(hw + (size_t)s * DD + cbase);
    #pragma unroll
    for (int j = 0; j < 8; ++j) acc[j] = fmaf(wgt, bf2f(hv[j]), acc[j]);
  }
  ushortx8 rv = *(const ushortx8*)(Xbf + (size_t)n * DD + cbase);
  floatx8 v;
  float s = 0.f, sq = 0.f;
  #pragma unroll
  for (int j = 0; j < 8; ++j) {
    float g = acc[j] + bias[cbase + j];
    float t = fmaxf(g, 0.f) + bf2f(rv[j]);
    v[j] = t;
    s += t; sq += t * t;
  }
  s = wave_allreduce_sum(s);
  sq = wave_allreduce_sum(sq);
  float mu = s * (1.f / DD);
  float var = sq * (1.f / DD) - mu * mu;
  float rstd = rsqrtf(var + 1e-5f);
  if (outf) {
    float4* o4 = (float4*)(outf + (size_t)n * DD + cbase);
    float4 oa, ob4;
    oa.x = fmaf((v[0] - mu) * rstd, gamma[cbase + 0], beta[cbase + 0]);
    oa.y = fmaf((v[1] - mu) * rstd, gamma[cbase + 1], beta[cbase + 1]);
    oa.z = fmaf((v[2] - mu) * rstd, gamma[cbase + 2], beta[cbase + 2]);
    oa.w = fmaf((v[3] - mu) * rstd, gamma[cbase + 3], beta[cbase + 3]);
    ob4.x = fmaf((v[4] - mu) * rstd, gamma[cbase + 4], beta[cbase + 4]);
    ob4.y = fmaf((v[5] - mu) * rstd, gamma[cbase + 5], beta[cbase + 5]);
    ob4.z = fmaf((v[6] - mu) * rstd, gamma[cbase + 6], beta[cbase + 6]);
    ob4.w = fmaf((v[7] - mu) * rstd, gamma[cbase + 7], beta[cbase + 7]);
    o4[0] = oa;
    o4[1] = ob4;
  } else {
    ushortx8 ob;
    #pragma unroll
    for (int j = 0; j < 8; ++j)
      ob[j] = f2bf(fmaf((v[j] - mu) * rstd, gamma[cbase + j], beta[cbase + j]));
    *(ushortx8*)(Xbf + (size_t)n * DD + cbase) = ob;
  }
}

// ---------------- host-side launcher ----------------
static void launch_bgemm(const unsigned short* A, const unsigned short* Bt,
                         const float* bias, void* C, int M, int Nc, int K,
                         int act, int outbf, hipStream_t stream) {
  dim3 grid(Nc / 128, M / 128);
  k_bgemm<<<grid, 256, 0, stream>>>(A, Bt, bias, C, M, Nc, K, act, outbf);
}

extern "C" void kernel_launch(void* const* d_in, const int* in_sizes, int n_in,
                              void* d_out, int out_size, void* d_ws, size_t ws_size,
                              hipStream_t stream) {
  const float* x       = (const float*)d_in[0];
  const int*   eidx    = (const int*)d_in[1];
  const float* eattr   = (const float*)d_in[2];
  const float* Wproj   = (const float*)d_in[3];
  const float* bproj   = (const float*)d_in[4];
  const float* geW     = (const float*)d_in[5];
  const float* geb     = (const float*)d_in[6];
  const float* gW1     = (const float*)d_in[7];
  const float* gb1     = (const float*)d_in[8];
  const float* gW2     = (const float*)d_in[9];
  const float* gb2     = (const float*)d_in[10];
  const float* gatWl   = (const float*)d_in[11];
  const float* gatbl   = (const float*)d_in[12];
  const float* gatWr   = (const float*)d_in[13];
  const float* gatbr   = (const float*)d_in[14];
  const float* gateW   = (const float*)d_in[15];
  const float* gatatt  = (const float*)d_in[16];
  const float* gatbias = (const float*)d_in[17];
  const float* gcn1W   = (const float*)d_in[18];
  const float* gcn1b   = (const float*)d_in[19];
  const float* gcn2W   = (const float*)d_in[20];
  const float* gcn2b   = (const float*)d_in[21];
  const float* lgamma  = (const float*)d_in[22];
  const float* lbeta   = (const float*)d_in[23];
  const int* srcArr = eidx;
  const int* dstArr = eidx + EE;

  // ---- workspace carving (~121 MB) ----
  char* p = (char*)d_ws;
  float* B            = (float*)p;          p += (size_t)NN * DD * 4;        // 32MB
  unsigned short* Xbf = (unsigned short*)p; p += (size_t)NN * DD * 2;        // 16MB
  unsigned short* U   = (unsigned short*)p; p += (size_t)NN * 2048 * 2;      // 64MB union
  unsigned short* w1t = (unsigned short*)p; p += (size_t)1024 * 512 * 2;
  unsigned short* w2t = (unsigned short*)p; p += (size_t)512 * 1024 * 2;
  unsigned short* wc0 = (unsigned short*)p; p += (size_t)2048 * 512 * 2;
  unsigned short* wc1 = (unsigned short*)p; p += (size_t)2048 * 512 * 2;
  unsigned short* g1t = (unsigned short*)p; p += (size_t)512 * 512 * 2;
  unsigned short* g2t = (unsigned short*)p; p += (size_t)512 * 512 * 2;
  float4* ea4     = (float4*)p;         p += (size_t)(EE + 4) * 16;      // 1MB (16B aligned)
  float* bc0      = (float*)p;          p += 2048 * 4;
  float* bc1      = (float*)p;          p += 2048 * 4;
  float* macc     = (float*)p;          p += 4 * 4;
  float* dinv     = (float*)p;          p += (size_t)NN * 4;
  float* dinv_src = (float*)p;          p += (size_t)(EE + 16) * 4;
  int*   cnt      = (int*)p;            p += (size_t)NN * 4;
  int*   offs     = (int*)p;            p += (size_t)(NN + 1) * 4 + 12;
  int*   cursor   = (int*)p;            p += (size_t)NN * 4;
  int*   srcs     = (int*)p;            p += (size_t)(EE + 16) * 4;

  unsigned short* Zbf = U;                    // NN x 512 (GINE agg out)
  unsigned short* Ybf = U + (size_t)NN * 512; // NN x 1024 (MLP mid)
  unsigned short* XLR = U;                    // NN x 2048 (GAT xl|xr, 2 heads)
  unsigned short* hw  = U;                    // NN x 512 (GCN h@W)

  hipMemsetAsync(cnt, 0, NN * sizeof(int), stream);
  hipMemsetAsync(cursor, 0, NN * sizeof(int), stream);
  hipMemsetAsync(macc, 0, 4 * sizeof(float), stream);

  k_count<<<EE / 256, 256, 0, stream>>>(dstArr, cnt);
  k_scan<<<1, 256, 0, stream>>>(cnt, offs);
  k_fill<<<EE / 256, 256, 0, stream>>>(dstArr, srcArr, eattr, offs, cursor, srcs, ea4);
  k_dinv<<<NN / 256, 256, 0, stream>>>(cnt, dinv);
  k_dsrc<<<EE / 256, 256, 0, stream>>>(srcs, dinv, dinv_src);
  k_edge_mean<<<64, 256, 0, stream>>>(eattr, macc);

  // weight prep
  {
    k_transcast<<<dim3(1024 / 32, 512 / 32), 256, 0, stream>>>(gW1, 1024, w1t, 512, 1024);
    k_transcast<<<dim3(512 / 32, 1024 / 32), 256, 0, stream>>>(gW2, 512, w2t, 1024, 512);
    k_transcast<<<dim3(1024 / 32, 512 / 32), 256, 0, stream>>>(gatWl, 2048, wc0, 512, 1024);
    k_transcast<<<dim3(1024 / 32, 512 / 32), 256, 0, stream>>>(gatWr, 2048, wc0 + (size_t)1024 * 512, 512, 1024);
    k_transcast<<<dim3(1024 / 32, 512 / 32), 256, 0, stream>>>(gatWl + 1024, 2048, wc1, 512, 1024);
    k_transcast<<<dim3(1024 / 32, 512 / 32), 256, 0, stream>>>(gatWr + 1024, 2048, wc1 + (size_t)1024 * 512, 512, 1024);
    k_transcast<<<dim3(512 / 32, 512 / 32), 256, 0, stream>>>(gcn1W, 512, g1t, 512, 512);
    k_transcast<<<dim3(512 / 32, 512 / 32), 256, 0, stream>>>(gcn2W, 512, g2t, 512, 512);
    k_bcomb<<<16, 256, 0, stream>>>(gatbl, gatbr, bc0, bc1);
  }

  // input projection (bf16 only)
  k_proj<<<NN * DD / 256, 256, 0, stream>>>(x, Wproj, bproj, Xbf);

  // ---- layer 0: GINEConv + MLP + LN ----
  k_gine_agg<<<NN / 4, 256, 0, stream>>>(Xbf, srcs, ea4, geW, geb, offs, Zbf);
  launch_bgemm(Zbf, w1t, gb1, Ybf, NN, 1024, 512, 1, 1, stream);
  launch_bgemm(Ybf, w2t, gb2, B, NN, 512, 1024, 0, 0, stream);
  k_ln0<<<NN / 4, 256, 0, stream>>>(B, Xbf, lgamma, lbeta, Xbf);

  // ---- layer 1: GATv2, two 2-head batches; per-(node,head) waves ----
  for (int b = 0; b < 2; ++b) {
    launch_bgemm(Xbf, b ? wc1 : wc0, b ? bc1 : bc0, XLR, NN, 2048, 512, 0, 1, stream);
    k_gat_fused<<<NN / 2, 256, 0, stream>>>(XLR, srcs, offs, ea4, macc,
                                            gateW, gatatt, B, Xbf, gatbias,
                                            lgamma + DD, lbeta + DD, b);
  }

  // ---- layers 2,3: GCN (aggregate + fused LN) ----
  launch_bgemm(Xbf, g1t, nullptr, hw, NN, 512, 512, 0, 1, stream);
  k_gcn_ln<<<NN / 4, 256, 0, stream>>>(hw, srcs, offs, dinv_src, dinv, gcn1b,
                                       lgamma + 2 * DD, lbeta + 2 * DD, Xbf, nullptr);
  launch_bgemm(Xbf, g2t, nullptr, hw, NN, 512, 512, 0, 1, stream);
  k_gcn_ln<<<NN / 4, 256, 0, stream>>>(hw, srcs, offs, dinv_src, dinv, gcn2b,
                                       lgamma + 3 * DD, lbeta + 3 * DD, Xbf, (float*)d_out);
}